// Round 11
// baseline (81.319 us; speedup 1.0000x reference)
//
#include <hip/hip_runtime.h>

#define NN 2048
#define NT 256
#define NB 4
#define NC 16
#define NCLS (NB * NC)
#define TILE 64
#define NTILES (NN / TILE)
#define KKEEP 176       // >= (K-1) + 64 = 163

typedef unsigned long long u64;

// orderable(score): ascending u32 == descending score
__device__ __forceinline__ unsigned score_hi(float s) {
  unsigned u = __float_as_uint(s);
  u ^= (u >> 31) ? 0xFFFFFFFFu : 0x80000000u;  // ascending-orderable
  return ~u;                                   // descending score
}
__device__ __forceinline__ float hi_score(unsigned hiw) {
  unsigned u = ~hiw;
  unsigned bits = (u >> 31) ? (u ^ 0x80000000u) : ~u;
  return __uint_as_float(bits);
}

// IoU with the exact op order of the reference; asm guard blocks
// ffp-contract from fusing (ka + a - iw*ih) into an FMA.
__device__ __forceinline__ float iou_f(float kx1, float ky1, float kx2, float ky2, float ka,
                                       float x1, float y1, float x2, float y2, float a) {
  float ix1 = fmaxf(kx1, x1);
  float iy1 = fmaxf(ky1, y1);
  float ix2 = fminf(kx2, x2);
  float iy2 = fminf(ky2, y2);
  float iw = fmaxf(ix2 - ix1, 0.0f);
  float ih = fmaxf(iy2 - iy1, 0.0f);
  float inter = iw * ih;
  asm volatile("" : "+v"(inter));
  float denom = ka + a - inter;
  return inter / denom;
}

// compare one broadcast key against this thread's 4 elements
#define CMPK(HI, J, CC) do {                                   \
  u64 kj = ((u64)(HI) << 32) | (unsigned)(J);                  \
  CC[0] += (kj < my[0]); CC[1] += (kj < my[1]);                \
  CC[2] += (kj < my[2]); CC[3] += (kj < my[3]);                \
} while (0)

// ---------------- kernel 1: rank sort, E=4 x split-4 LDS broadcast ----------
// 512 blocks = 64 classes x 8 chunks of 256 elements. Each thread owns 4
// elements (ln + i*64); wave wv scans key-quarter wv (128 b128 reads) for all
// of them -> each broadcast read is amortized over 256 element-compares.
// u16 partials in LDS; wave wv finalizes element-group wv and scatters.
// Floors: LDS 8w x 128 x 12cyc ~ 5.1us, VALU ~ 7.7us chip-wide.
__global__ __launch_bounds__(NT) void rank_kernel(
    const float* __restrict__ scores,
    const float* __restrict__ boxes,
    float4* __restrict__ wbox,
    float* __restrict__ wsc, int* __restrict__ widx)
{
  __shared__ unsigned s_hi[NN];                    // 8 KB
  __shared__ unsigned short s_part[4][4][64];      // [elem-grp][key-q][lane] 2 KB

  const int blk = blockIdx.x;
  const int bc  = blk >> 3;        // class id 0..63
  const int cb  = (blk & 7) * 256; // element chunk base
  const int b   = bc >> 4;         // batch
  const int t   = threadIdx.x;
  const int wv  = t >> 6;
  const int ln  = t & 63;

  const float* __restrict__ scls = scores + (size_t)bc * NN;

  // stage orderable hi-words (coalesced float4 loads, b128 stores)
  {
    const float4* s4 = (const float4*)scls;
    uint4* d4 = (uint4*)s_hi;
    float4 v = s4[t];
    d4[t] = make_uint4(score_hi(v.x), score_hi(v.y), score_hi(v.z), score_hi(v.w));
    v = s4[t + 256];
    d4[t + 256] = make_uint4(score_hi(v.x), score_hi(v.y), score_hi(v.z), score_hi(v.w));
  }
  __syncthreads();

  // my 4 elements (stride-64 within the chunk; stride-1 LDS reads per lane)
  u64 my[4];
#pragma unroll
  for (int i = 0; i < 4; i++) {
    const int e = cb + ln + i * 64;
    my[i] = ((u64)s_hi[e] << 32) | (unsigned)e;
  }

  // scan key-quarter wv for all 4 elements
  int c0[4] = {0, 0, 0, 0}, c1[4] = {0, 0, 0, 0};
  const uint4* k4 = (const uint4*)s_hi;
  const int kbase = wv * 128;      // uint4 units
#pragma unroll 2
  for (int jc = 0; jc < 64; jc++) {
    const uint4 ka = k4[kbase + 2 * jc];       // uniform b128 broadcast
    const uint4 kb = k4[kbase + 2 * jc + 1];
    const int j = wv * 512 + jc * 8;
    CMPK(ka.x, j + 0, c0); CMPK(ka.y, j + 1, c1);
    CMPK(ka.z, j + 2, c0); CMPK(ka.w, j + 3, c1);
    CMPK(kb.x, j + 4, c0); CMPK(kb.y, j + 5, c1);
    CMPK(kb.z, j + 6, c0); CMPK(kb.w, j + 7, c1);
  }
#pragma unroll
  for (int i = 0; i < 4; i++)
    s_part[i][wv][ln] = (unsigned short)(c0[i] + c1[i]);
  __syncthreads();

  // wave wv finalizes element-group wv: sum 4 partials, gather box, scatter
  const int el = cb + ln + wv * 64;
  const int rank = (int)s_part[wv][0][ln] + (int)s_part[wv][1][ln] +
                   (int)s_part[wv][2][ln] + (int)s_part[wv][3][ln];
  const unsigned h = s_hi[el];
  float4 v = *(const float4*)(boxes + ((size_t)b * NN + el) * 4);
  float x1 = fminf(v.x, v.z), x2 = fmaxf(v.x, v.z);
  float y1 = fminf(v.y, v.w), y2 = fmaxf(v.y, v.w);
  const size_t o = (size_t)bc * NN + rank;
  wbox[o] = make_float4(x1, y1, x2, y2);
  wsc[o]  = hi_score(h);
  widx[o] = el;
}

// ---------------- kernel 2: single-wave per-class greedy NMS ----------------
// 64 blocks x 64 threads. Lane = column; full intra-tile column mask lives in
// the lane (no cross-wave combine), ballots do the greedy resolve, barriers
// are 1-wave (cheap). Kept list in LDS for the dead-check.
__global__ __launch_bounds__(64) void greedy_kernel(
    const float4* __restrict__ wbox,
    const float* __restrict__ wsc, const int* __restrict__ widx,
    const float* __restrict__ iou_thr_p, const float* __restrict__ score_thr_p,
    int K, int* __restrict__ out)
{
  __shared__ float4 s_kbox[KKEEP];
  __shared__ float  s_ka[KKEEP];
  __shared__ float4 s_tb[TILE];

  const int bc = blockIdx.x;
  const int b  = bc >> 4;
  const int c  = bc & 15;
  const int ln = threadIdx.x;

  const float iou_thr = *iou_thr_p;
  const float sthr    = *score_thr_p;

  int* orow = out + (size_t)bc * K * 3;
  for (int i = ln; i < K * 3; i += 64) orow[i] = -1;

  const size_t base0 = (size_t)bc * NN;

  // tile 0 into registers
  float4 jb  = wbox[base0 + ln];
  float  jsc = wsc[base0 + ln];
  int    jidx = widx[base0 + ln];

  int total = 0;
  for (int tile = 0; tile < NTILES; tile++) {
    s_tb[ln] = jb;
    const float ja = (jb.z - jb.x) * (jb.w - jb.y);   // reference op order
    const int kct = total;
    __syncthreads();   // 1-wave barrier: makes s_tb/s_kbox writes visible

    // prefetch next tile (VMEM latency hides under compute below)
    float4 nb = jb; float ns = jsc; int ni = jidx;
    if (tile + 1 < NTILES) {
      nb = wbox[base0 + (tile + 1) * TILE + ln];
      ns = wsc [base0 + (tile + 1) * TILE + ln];
      ni = widx[base0 + (tile + 1) * TILE + ln];
    }

    // dead-check vs accumulated kept list
    bool dead = false;
    for (int ki = 0; ki < kct; ki++) {
      const float4 kb = s_kbox[ki];
      const float iou = iou_f(kb.x, kb.y, kb.z, kb.w, s_ka[ki],
                              jb.x, jb.y, jb.z, jb.w, ja);
      if (iou > iou_thr) { dead = true; break; }
    }

    // intra-tile upper-triangle column mask (rows il < ln)
    u64 m = 0ULL;
    for (int il = 0; il < TILE - 1; il++) {
      if (il < ln) {
        const float4 rb = s_tb[il];                   // uniform b128 broadcast
        const float ra = (rb.z - rb.x) * (rb.w - rb.y);
        const float iou = iou_f(rb.x, rb.y, rb.z, rb.w, ra,
                                jb.x, jb.y, jb.z, jb.w, ja);
        if (iou > iou_thr) m |= (1ULL << il);
      }
    }

    // greedy resolve via ballots
    u64 alive = __ballot(!dead);
    for (int i2 = 0; i2 < TILE; i2++) {
      if ((alive >> i2) & 1ULL) {
        const u64 kill = __ballot((int)((m >> i2) & 1ULL));
        alive &= ~kill;
      }
    }

    const bool kept = (alive >> ln) & 1ULL;
    const int pos = __popcll(alive & ((1ULL << ln) - 1ULL));
    if (kept) {
      const int kpos = total + pos;                   // <= 99 + 63 < KKEEP
      s_kbox[kpos] = jb;
      s_ka[kpos]   = ja;
      if (kpos < K && jsc >= sthr) {
        orow[kpos * 3 + 0] = b;
        orow[kpos * 3 + 1] = c;
        orow[kpos * 3 + 2] = jidx;
      }
    }
    total += (int)__popcll(alive);
    __syncthreads();   // kept-list writes visible before next dead-check
    if (total >= K) break;
    jb = nb; jsc = ns; jidx = ni;
  }
}

extern "C" void kernel_launch(void* const* d_in, const int* in_sizes, int n_in,
                              void* d_out, int out_size, void* d_ws, size_t ws_size,
                              hipStream_t stream) {
  const float* boxes  = (const float*)d_in[0];
  const float* scores = (const float*)d_in[1];
  const float* iou_p  = (const float*)d_in[3];
  const float* sth_p  = (const float*)d_in[4];
  int* out = (int*)d_out;

  const int K = out_size / (NCLS * 3);
  const size_t plane = (size_t)NCLS * NN;

  float4* wbox = (float4*)d_ws;                 // 2 MB
  float*  wsc  = (float*)(wbox + plane);
  int*    widx = (int*)(wsc + plane);

  hipLaunchKernelGGL(rank_kernel, dim3(NCLS * 8), dim3(NT), 0, stream,
                     scores, boxes, wbox, wsc, widx);
  hipLaunchKernelGGL(greedy_kernel, dim3(NCLS), dim3(64), 0, stream,
                     wbox, wsc, widx, iou_p, sth_p, K, out);
}

// Round 12
// 57.329 us; speedup vs baseline: 1.4185x; 1.4185x over previous
//
#include <hip/hip_runtime.h>

#define NN 2048
#define NT 256
#define NB 4
#define NC 16
#define NCLS (NB * NC)
#define TILE 64
#define NTILES (NN / TILE)
#define PRE 256         // prefix length resolved via bitmask (kept(PRE) >> K here)
#define KKEEP 176       // fallback kept-list cap: kept<K=100 entering, +63/tile

typedef unsigned long long u64;

// orderable(score): ascending u32 == descending score
__device__ __forceinline__ unsigned score_hi(float s) {
  unsigned u = __float_as_uint(s);
  u ^= (u >> 31) ? 0xFFFFFFFFu : 0x80000000u;  // ascending-orderable
  return ~u;                                   // descending score
}
__device__ __forceinline__ float hi_score(unsigned hiw) {
  unsigned u = ~hiw;
  unsigned bits = (u >> 31) ? (u ^ 0x80000000u) : ~u;
  return __uint_as_float(bits);
}

// IoU with the exact op order of the reference; asm guard blocks
// ffp-contract from fusing (ka + a - iw*ih) into an FMA.
__device__ __forceinline__ float iou_f(float kx1, float ky1, float kx2, float ky2, float ka,
                                       float x1, float y1, float x2, float y2, float a) {
  float ix1 = fmaxf(kx1, x1);
  float iy1 = fmaxf(ky1, y1);
  float ix2 = fminf(kx2, x2);
  float iy2 = fminf(ky2, y2);
  float iw = fmaxf(ix2 - ix1, 0.0f);
  float ih = fmaxf(iy2 - iy1, 0.0f);
  float inter = iw * ih;
  asm volatile("" : "+v"(inter));
  float denom = ka + a - inter;
  return inter / denom;
}

// compare one broadcast key against this thread's 4 elements
#define CMPK(HI, J, CC) do {                                   \
  u64 kj = ((u64)(HI) << 32) | (unsigned)(J);                  \
  CC[0] += (kj < my[0]); CC[1] += (kj < my[1]);                \
  CC[2] += (kj < my[2]); CC[3] += (kj < my[3]);                \
} while (0)

// ---------------- kernel 1: rank sort, E=4 x split-4 LDS broadcast ----------
// (unchanged from R11 -- measured ~26us)
__global__ __launch_bounds__(NT) void rank_kernel(
    const float* __restrict__ scores,
    const float* __restrict__ boxes,
    float4* __restrict__ wbox,
    float* __restrict__ wsc, int* __restrict__ widx)
{
  __shared__ unsigned s_hi[NN];                    // 8 KB
  __shared__ unsigned short s_part[4][4][64];      // [elem-grp][key-q][lane]

  const int blk = blockIdx.x;
  const int bc  = blk >> 3;        // class id 0..63
  const int cb  = (blk & 7) * 256; // element chunk base
  const int b   = bc >> 4;         // batch
  const int t   = threadIdx.x;
  const int wv  = t >> 6;
  const int ln  = t & 63;

  const float* __restrict__ scls = scores + (size_t)bc * NN;

  {
    const float4* s4 = (const float4*)scls;
    uint4* d4 = (uint4*)s_hi;
    float4 v = s4[t];
    d4[t] = make_uint4(score_hi(v.x), score_hi(v.y), score_hi(v.z), score_hi(v.w));
    v = s4[t + 256];
    d4[t + 256] = make_uint4(score_hi(v.x), score_hi(v.y), score_hi(v.z), score_hi(v.w));
  }
  __syncthreads();

  u64 my[4];
#pragma unroll
  for (int i = 0; i < 4; i++) {
    const int e = cb + ln + i * 64;
    my[i] = ((u64)s_hi[e] << 32) | (unsigned)e;
  }

  int c0[4] = {0, 0, 0, 0}, c1[4] = {0, 0, 0, 0};
  const uint4* k4 = (const uint4*)s_hi;
  const int kbase = wv * 128;
#pragma unroll 2
  for (int jc = 0; jc < 64; jc++) {
    const uint4 ka = k4[kbase + 2 * jc];
    const uint4 kb = k4[kbase + 2 * jc + 1];
    const int j = wv * 512 + jc * 8;
    CMPK(ka.x, j + 0, c0); CMPK(ka.y, j + 1, c1);
    CMPK(ka.z, j + 2, c0); CMPK(ka.w, j + 3, c1);
    CMPK(kb.x, j + 4, c0); CMPK(kb.y, j + 5, c1);
    CMPK(kb.z, j + 6, c0); CMPK(kb.w, j + 7, c1);
  }
#pragma unroll
  for (int i = 0; i < 4; i++)
    s_part[i][wv][ln] = (unsigned short)(c0[i] + c1[i]);
  __syncthreads();

  const int el = cb + ln + wv * 64;
  const int rank = (int)s_part[wv][0][ln] + (int)s_part[wv][1][ln] +
                   (int)s_part[wv][2][ln] + (int)s_part[wv][3][ln];
  const unsigned h = s_hi[el];
  float4 v = *(const float4*)(boxes + ((size_t)b * NN + el) * 4);
  float x1 = fminf(v.x, v.z), x2 = fmaxf(v.x, v.z);
  float y1 = fminf(v.y, v.w), y2 = fmaxf(v.y, v.w);
  const size_t o = (size_t)bc * NN + rank;
  wbox[o] = make_float4(x1, y1, x2, y2);
  wsc[o]  = hi_score(h);
  widx[o] = el;
}

// ---------------- kernel 2: prefix IoU bitmask (256x256 upper-tri) ----------
// 256 blocks = 64 classes x 4 row-quarters; thread = column j (256/block).
// colmask word q, bit r: IoU(row q*64+r, col j) > thr  (only rows < j).
__global__ __launch_bounds__(NT) void mask_kernel(
    const float4* __restrict__ wbox,
    const float* __restrict__ iou_thr_p,
    u64* __restrict__ cm)
{
  __shared__ float4 s_pb[PRE];
  __shared__ float  s_pa[PRE];

  const int bc = blockIdx.x >> 2;  // class
  const int q  = blockIdx.x & 3;   // row quarter
  const int j  = threadIdx.x;      // column

  const float iou_thr = *iou_thr_p;
  const size_t base0 = (size_t)bc * NN;

  const float4 bj = wbox[base0 + j];
  s_pb[j] = bj;
  s_pa[j] = (bj.z - bj.x) * (bj.w - bj.y);     // reference op order
  __syncthreads();

  const float ja = s_pa[j];
  u64 m = 0ULL;
  if (j > q * 64) {                            // wave-uniform skip for q>0
    const int rbase = q * 64;
#pragma unroll 4
    for (int r = 0; r < 64; r++) {
      const int i = rbase + r;
      if (i < j) {
        const float4 rb = s_pb[i];             // uniform b128 broadcast
        const float iou = iou_f(rb.x, rb.y, rb.z, rb.w, s_pa[i],
                                bj.x, bj.y, bj.z, bj.w, ja);
        if (iou > iou_thr) m |= (1ULL << r);
      }
    }
  }
  cm[((size_t)bc * PRE + j) * 4 + q] = m;
}

// ---------------- kernel 3: bitmask greedy resolve + output ----------------
// 64 blocks x 1 wave. Lane l owns cols {l, 64+l, 128+l, 192+l}; colmasks in
// 32 VGPRs. 256-row sweep: readlane aliveness + 4 bit-ops per row. No IoU.
// Fallback (kept<K after PRE): R11-style tiled IoU greedy -- correctness only.
__global__ __launch_bounds__(64) void resolve_kernel(
    const float4* __restrict__ wbox,
    const float* __restrict__ wsc, const int* __restrict__ widx,
    const u64* __restrict__ cm,
    const float* __restrict__ iou_thr_p, const float* __restrict__ score_thr_p,
    int K, int* __restrict__ out)
{
  __shared__ float4 s_kbox[KKEEP];
  __shared__ float  s_ka[KKEEP];
  __shared__ float4 s_tb[TILE];

  const int bc = blockIdx.x;
  const int b  = bc >> 4;
  const int c  = bc & 15;
  const int ln = threadIdx.x;

  const float iou_thr = *iou_thr_p;
  const float sthr    = *score_thr_p;
  const size_t base0 = (size_t)bc * NN;

  int* orow = out + (size_t)bc * K * 3;
  for (int i = ln; i < K * 3; i += 64) orow[i] = -1;

  // load colmasks: cmv[slot][word]
  u64 cmv[4][4];
#pragma unroll
  for (int g = 0; g < 4; g++) {
    const u64* p = cm + ((size_t)bc * PRE + g * 64 + ln) * 4;
    cmv[g][0] = p[0]; cmv[g][1] = p[1]; cmv[g][2] = p[2]; cmv[g][3] = p[3];
  }

  int d0 = 0, d1 = 0, d2 = 0, d3 = 0;   // dead flags for the 4 owned cols

  // ordered sweep over 256 prefix rows
#pragma unroll
  for (int g = 0; g < 4; g++) {
    for (int l2 = 0; l2 < 64; l2++) {
      int dsrc = (g == 0) ? d0 : (g == 1) ? d1 : (g == 2) ? d2 : d3;
      const int rowdead = __builtin_amdgcn_readlane(dsrc, l2);
      if (!rowdead) {                    // uniform branch
        d0 |= (int)((cmv[0][g] >> l2) & 1ULL);
        d1 |= (int)((cmv[1][g] >> l2) & 1ULL);
        d2 |= (int)((cmv[2][g] >> l2) & 1ULL);
        d3 |= (int)((cmv[3][g] >> l2) & 1ULL);
      }
    }
  }

  // emit output for prefix kept boxes
  int total = 0;
#pragma unroll
  for (int g = 0; g < 4; g++) {
    const int dg = (g == 0) ? d0 : (g == 1) ? d1 : (g == 2) ? d2 : d3;
    const u64 kg = ~__ballot(dg);
    const bool kept = (kg >> ln) & 1ULL;
    if (kept) {
      const int kpos = total + (int)__popcll(kg & ((1ULL << ln) - 1ULL));
      if (kpos < K) {
        const int cidx = g * 64 + ln;
        const float sc = wsc[base0 + cidx];
        if (sc >= sthr) {
          orow[kpos * 3 + 0] = b;
          orow[kpos * 3 + 1] = c;
          orow[kpos * 3 + 2] = widx[base0 + cidx];
        }
      }
    }
    total += (int)__popcll(kg);
  }

  if (total >= K) return;                // the hot path ends here

  // ---------------- fallback: continue tiled greedy past PRE ----------------
  {
    int run = 0;
#pragma unroll
    for (int g = 0; g < 4; g++) {
      const int dg = (g == 0) ? d0 : (g == 1) ? d1 : (g == 2) ? d2 : d3;
      const u64 kg = ~__ballot(dg);
      if ((kg >> ln) & 1ULL) {
        const int kpos = run + (int)__popcll(kg & ((1ULL << ln) - 1ULL));
        const float4 bb = wbox[base0 + g * 64 + ln];
        s_kbox[kpos] = bb;
        s_ka[kpos]   = (bb.z - bb.x) * (bb.w - bb.y);
      }
      run += (int)__popcll(kg);
    }
    __syncthreads();

    for (int tile = PRE / TILE; tile < NTILES && total < K; tile++) {
      const float4 jb  = wbox[base0 + tile * TILE + ln];
      const float  jsc = wsc [base0 + tile * TILE + ln];
      const int    jidx = widx[base0 + tile * TILE + ln];
      const float  ja  = (jb.z - jb.x) * (jb.w - jb.y);
      s_tb[ln] = jb;
      __syncthreads();

      bool dead = false;
      for (int ki = 0; ki < total; ki++) {
        const float4 kb = s_kbox[ki];
        const float iou = iou_f(kb.x, kb.y, kb.z, kb.w, s_ka[ki],
                                jb.x, jb.y, jb.z, jb.w, ja);
        if (iou > iou_thr) { dead = true; break; }
      }

      u64 m = 0ULL;
      for (int il = 0; il < TILE - 1; il++) {
        if (il < ln) {
          const float4 rb = s_tb[il];
          const float ra = (rb.z - rb.x) * (rb.w - rb.y);
          const float iou = iou_f(rb.x, rb.y, rb.z, rb.w, ra,
                                  jb.x, jb.y, jb.z, jb.w, ja);
          if (iou > iou_thr) m |= (1ULL << il);
        }
      }

      u64 alive = __ballot(!dead);
      for (int i2 = 0; i2 < TILE; i2++) {
        if ((alive >> i2) & 1ULL) {
          const u64 kill = __ballot((int)((m >> i2) & 1ULL));
          alive &= ~kill;
        }
      }

      const bool kept = (alive >> ln) & 1ULL;
      const int pos = (int)__popcll(alive & ((1ULL << ln) - 1ULL));
      if (kept) {
        const int kpos = total + pos;    // total<K<=100, +63 < KKEEP
        s_kbox[kpos] = jb;
        s_ka[kpos]   = ja;
        if (kpos < K && jsc >= sthr) {
          orow[kpos * 3 + 0] = b;
          orow[kpos * 3 + 1] = c;
          orow[kpos * 3 + 2] = jidx;
        }
      }
      total += (int)__popcll(alive);
      __syncthreads();
    }
  }
}

extern "C" void kernel_launch(void* const* d_in, const int* in_sizes, int n_in,
                              void* d_out, int out_size, void* d_ws, size_t ws_size,
                              hipStream_t stream) {
  const float* boxes  = (const float*)d_in[0];
  const float* scores = (const float*)d_in[1];
  const float* iou_p  = (const float*)d_in[3];
  const float* sth_p  = (const float*)d_in[4];
  int* out = (int*)d_out;

  const int K = out_size / (NCLS * 3);
  const size_t plane = (size_t)NCLS * NN;

  float4* wbox = (float4*)d_ws;                 // 2 MB
  float*  wsc  = (float*)(wbox + plane);        // 512 KB
  int*    widx = (int*)(wsc + plane);           // 512 KB
  u64*    cm   = (u64*)(widx + plane);          // 64*256*4*8 = 512 KB

  hipLaunchKernelGGL(rank_kernel, dim3(NCLS * 8), dim3(NT), 0, stream,
                     scores, boxes, wbox, wsc, widx);
  hipLaunchKernelGGL(mask_kernel, dim3(NCLS * 4), dim3(NT), 0, stream,
                     wbox, iou_p, cm);
  hipLaunchKernelGGL(resolve_kernel, dim3(NCLS), dim3(64), 0, stream,
                     wbox, wsc, widx, cm, iou_p, sth_p, K, out);
}